// Round 2
// baseline (17404.994 us; speedup 1.0000x reference)
//
#include <hip/hip_runtime.h>

#define B_ 128
#define T_ 256
#define F_ 128
#define H_ 768
#define NG 3072      // 4*H
#define BH (B_*H_)
#define UPT 16

typedef short s16x8 __attribute__((ext_vector_type(8)));
typedef float f32x4 __attribute__((ext_vector_type(4)));

__device__ __forceinline__ unsigned short f2bf(float x) {
  unsigned u = __float_as_uint(x);
  u += 0x7fffu + ((u >> 16) & 1u);
  return (unsigned short)(u >> 16);
}

__device__ __forceinline__ void async16(const void* g, void* l) {
  __builtin_amdgcn_global_load_lds(
      (const __attribute__((address_space(1))) void*)g,
      (__attribute__((address_space(3))) void*)l, 16, 0, 0);
}

// ---- flag array layout (ints): [0]=abort, cnt_h0[513][4], cnt_h1, done_h0, done_h1
#define FL_CNT_H0 1
#define FL_CNT_H1 (1 + 2052)
#define FL_DONE_H0 (1 + 4104)
#define FL_DONE_H1 (1 + 6156)
#define FL_TOTAL 8209

__device__ __forceinline__ int expdone_h0(int u) {
  return (u == 0) ? 48 : (u <= 256) ? 96 : (u <= 511) ? 98 : 48;
}
__device__ __forceinline__ int expdone_h1(int u) {
  return (u <= 256) ? 48 : (u <= 511) ? 98 : 2;
}

struct Seg {
  const unsigned short* a; long lda;
  const unsigned short* w;
  int nslab;
  int* flag;
};

struct Job {
  Seg seg[2];
  long ldw, wrow0;
  const float* bias;
  float* c;
  unsigned short* h;
  int* post;
  int* ring; int ringExp;
  int* done0; int* done1;
  float* yout;             // pre-offset by yt*F + ycol0
  const float* ybias;
  int isY, tm, tn, b0;
};

struct SMu {
  union {
    struct { unsigned short A[2][32*128]; unsigned short Bm[2][64*128]; } stg; // 48KB
    float gates[32][68];
  };
  int sres;
};

struct PP {
  const unsigned short* xbf;
  const unsigned short *Wenc0, *Wenc1, *Wdec0f, *Wext, *Wdec1, *linWbf;
  const float *benc0, *benc1, *bdec0f, *bext, *bdec1, *linb;
  unsigned short *h0ring, *h1ring;
  float *c0, *c1;
  int* flags;
  float* out;
};

__device__ bool spinwait_block(int* f, int exp, int* abortf, SMu& sm, int tid) {
  if (tid == 0) {
    int ok = 1, n = 0;
    while (__hip_atomic_load(f, __ATOMIC_RELAXED, __HIP_MEMORY_SCOPE_AGENT) < exp) {
      __builtin_amdgcn_s_sleep(8);
      if ((++n & 255) == 0) {
        if (__hip_atomic_load(abortf, __ATOMIC_RELAXED, __HIP_MEMORY_SCOPE_AGENT)) { ok = 0; break; }
        if (n > 4000000) {
          __hip_atomic_store(abortf, 1, __ATOMIC_RELAXED, __HIP_MEMORY_SCOPE_AGENT);
          ok = 0; break;
        }
      }
    }
    if (ok) {
      int v = __hip_atomic_load(f, __ATOMIC_ACQUIRE, __HIP_MEMORY_SCOPE_AGENT);
      ok = (v >= exp);
    }
    sm.sres = ok;
  }
  __syncthreads();
  return sm.sres != 0;
}

__device__ __forceinline__ void stage_slab(SMu& sm, int buf, int slab,
    const unsigned short* aptr, long lda, const unsigned short* wptr,
    long ldw, long wrow0, int b0, int wave, int lane) {
  int kk = slab * 128;
#pragma unroll
  for (int q = 0; q < 2; ++q) {              // A: 8KB = 8 chunks of 1KB
    int ch = wave*2 + q;
    int P = ch*1024 + lane*16;
    int r = P >> 8;                           // row 0..31
    int sl = ((P >> 4) & 15) ^ (r & 7);       // XOR-swizzled 16B slot
    const unsigned short* gp = aptr + (long)(b0 + r)*lda + kk + sl*8;
    async16(gp, (char*)(sm.stg.A[buf]) + ch*1024);
  }
#pragma unroll
  for (int q = 0; q < 4; ++q) {              // B: 16KB = 16 chunks
    int ch = wave*4 + q;
    int P = ch*1024 + lane*16;
    int r = P >> 8;                           // row 0..63
    int sl = ((P >> 4) & 15) ^ (r & 7);
    const unsigned short* gp = wptr + (wrow0 + r)*ldw + kk + sl*8;
    async16(gp, (char*)(sm.stg.Bm[buf]) + ch*1024);
  }
}

__device__ __forceinline__ void compute_slab(SMu& sm, int buf, f32x4 acc[2],
                                             int wm, int wn, int lane) {
  const char* At = (const char*)(sm.stg.A[buf]);
  const char* Bt = (const char*)(sm.stg.Bm[buf]);
#pragma unroll
  for (int ks = 0; ks < 4; ++ks) {
    int ar = wm*16 + (lane & 15);
    int as = (ks*4 + (lane >> 4)) ^ (ar & 7);
    s16x8 a = *(const s16x8*)(At + ar*256 + as*16);
#pragma unroll
    for (int nf = 0; nf < 2; ++nf) {
      int br = wn*32 + nf*16 + (lane & 15);
      int bsl = (ks*4 + (lane >> 4)) ^ (br & 7);
      s16x8 b = *(const s16x8*)(Bt + br*256 + bsl*16);
      acc[nf] = __builtin_amdgcn_mfma_f32_16x16x32_bf16(a, b, acc[nf], 0, 0, 0);
    }
  }
}

__device__ bool run_job(const Job& j, int* abortf, SMu& sm, int tid) {
  const int wave = tid >> 6, lane = tid & 63;
  const int wm = wave >> 1, wn = wave & 1;
  f32x4 acc[2] = {{0.f,0.f,0.f,0.f},{0.f,0.f,0.f,0.f}};

  for (int sg = 0; sg < 2; ++sg) {
    const Seg& g = j.seg[sg];
    if (g.nslab == 0) continue;
    if (g.flag) {
      if (!spinwait_block(g.flag, 48, abortf, sm, tid)) return false;
    }
    __syncthreads();                          // buffers free from previous use
    stage_slab(sm, 0, 0, g.a, g.lda, g.w, j.ldw, j.wrow0, j.b0, wave, lane);
    for (int it = 0; it < g.nslab; ++it) {
      __syncthreads();                        // drain vmcnt: slab `it` in LDS
      if (it + 1 < g.nslab)
        stage_slab(sm, (it+1)&1, it+1, g.a, g.lda, g.w, j.ldw, j.wrow0, j.b0, wave, lane);
      compute_slab(sm, it&1, acc, wm, wn, lane);
    }
  }

  // reader-completion bumps (all global reads of operands are complete here)
  if (tid == 0) {
    if (j.done0) __hip_atomic_fetch_add(j.done0, 1, __ATOMIC_RELAXED, __HIP_MEMORY_SCOPE_AGENT);
    if (j.done1) __hip_atomic_fetch_add(j.done1, 1, __ATOMIC_RELAXED, __HIP_MEMORY_SCOPE_AGENT);
  }

  if (j.isY) {
#pragma unroll
    for (int nf = 0; nf < 2; ++nf) {
      int col = wn*32 + nf*16 + (lane & 15);
      float bia = j.ybias[col];
#pragma unroll
      for (int rg = 0; rg < 4; ++rg) {
        int row = wm*16 + (lane >> 4)*4 + rg;
        j.yout[(long)(j.b0 + row)*(T_*F_) + col] = acc[nf][rg] + bia;
      }
    }
    return true;
  }

  __syncthreads();
#pragma unroll
  for (int nf = 0; nf < 2; ++nf) {
    int col = wn*32 + nf*16 + (lane & 15);
#pragma unroll
    for (int rg = 0; rg < 4; ++rg) {
      int row = wm*16 + (lane >> 4)*4 + rg;
      sm.gates[row][col] = acc[nf][rg];
    }
  }
  __syncthreads();

  if (j.ring) {
    if (!spinwait_block(j.ring, j.ringExp, abortf, sm, tid)) return false;
  }

  const float* bs0 = j.bias + (long)j.tn*64;
  for (int e = tid; e < 32*UPT; e += 256) {
    int bl = e >> 4, ul = e & 15;
    float gi = sm.gates[bl][ 0 + ul] + bs0[ 0 + ul];
    float gf = sm.gates[bl][16 + ul] + bs0[16 + ul];
    float gg = sm.gates[bl][32 + ul] + bs0[32 + ul];
    float go = sm.gates[bl][48 + ul] + bs0[48 + ul];
    float iv = 1.f / (1.f + __expf(-gi));
    float fv = 1.f / (1.f + __expf(-gf));
    float gc = fminf(fmaxf(gg, -15.f), 15.f);
    float eg = __expf(2.f * gc);
    float gv = (eg - 1.f) / (eg + 1.f);
    float ov = 1.f / (1.f + __expf(-go));
    long ci = (long)(j.b0 + bl)*H_ + (long)j.tn*16 + ul;
    float c2 = fv * j.c[ci] + iv * gv;
    j.c[ci] = c2;
    float cc = fminf(fmaxf(c2, -15.f), 15.f);
    float ec = __expf(2.f * cc);
    float th = (ec - 1.f) / (ec + 1.f);
    j.h[ci] = f2bf(ov * th);
  }
  __syncthreads();                            // drains each wave's stores
  if (tid == 0)
    __hip_atomic_fetch_add(j.post, 1, __ATOMIC_RELEASE, __HIP_MEMORY_SCOPE_AGENT);
  return true;
}

__device__ bool make_job(int s, int b, const PP& p, Job& j) {
  j.seg[0].nslab = 0; j.seg[1].nslab = 0;
  j.seg[0].flag = nullptr; j.seg[1].flag = nullptr;
  j.done0 = nullptr; j.done1 = nullptr; j.ring = nullptr; j.post = nullptr; j.isY = 0;
  int* Fl = p.flags;
  int* cnt_h0  = Fl + FL_CNT_H0;
  int* cnt_h1  = Fl + FL_CNT_H1;
  int* done_h0 = Fl + FL_DONE_H0;
  int* done_h1 = Fl + FL_DONE_H1;
  auto h0s = [&](int v){ return p.h0ring + (size_t)(v & 7)*BH; };
  auto h1s = [&](int v){ return p.h1ring + (size_t)(v & 7)*BH; };

  if (b < 200) {
    if (s <= 255) {                           // enc0(t=s)
      if (b >= 192) return false;
      int t = s, tm = b & 3, tn = b >> 2;
      j.tm=tm; j.tn=tn; j.b0=tm*32; j.ldw = F_+H_; j.wrow0 = (long)tn*64;
      j.seg[0] = { p.xbf + (long)t*F_, (long)T_*F_, p.Wenc0, 1, nullptr };
      j.seg[1] = { h0s(t), (long)H_, p.Wenc0 + F_, 6, (t>=1) ? cnt_h0 + (t*4+tm) : nullptr };
      j.bias = p.benc0; j.c = p.c0; j.h = h0s(t+1);
      j.post = cnt_h0 + ((t+1)*4+tm);
      if (t+1 >= 8) { j.ring = done_h0 + ((t-7)*4+tm); j.ringExp = expdone_h0(t-7); }
      j.done1 = done_h0 + (t*4+tm);
      return true;
    }
    if (s == 256) return false;
    if (s == 769) {                           // final y(T-1) -> out[:,0,:]
      if (b >= 8) return false;
      int tm = b & 3, tn = b >> 2;
      j.tm=tm; j.tn=tn; j.b0=tm*32; j.ldw = H_; j.wrow0 = (long)tn*64;
      j.seg[0] = { h1s(512), (long)H_, p.linWbf, 6, cnt_h1 + (512*4+tm) };
      j.isY = 1; j.ybias = p.linb + tn*64;
      j.yout = p.out + (long)tn*64;
      j.done0 = done_h1 + (512*4+tm);
      return true;
    }
    int d = s - 257;
    if (d & 1) return false;
    int t = d >> 1;
    if (t == 0) {                             // cd0(0): A=[x_last | h0_fin]
      if (b >= 192) return false;
      int tm = b & 3, tn = b >> 2;
      j.tm=tm; j.tn=tn; j.b0=tm*32; j.ldw = F_+H_; j.wrow0 = (long)tn*64;
      j.seg[0] = { p.xbf + (long)(T_-1)*F_, (long)T_*F_, p.Wdec0f, 1, nullptr };
      j.seg[1] = { h0s(256), (long)H_, p.Wdec0f + F_, 6, cnt_h0 + (256*4+tm) };
      j.bias = p.bdec0f; j.c = p.c0; j.h = h0s(257);
      j.post = cnt_h0 + (257*4+tm);
      j.ring = done_h0 + (249*4+tm); j.ringExp = expdone_h0(249);
      j.done1 = done_h0 + (256*4+tm);
      return true;
    }
    // cd0(t>=1): W_ext, early=h0 (stale), late=h1 (fresh)
    int tm = b & 3, tn = b >> 2;              // tn 0..49
    j.tm=tm; j.tn=tn; j.b0=tm*32; j.ldw = 2*H_; j.wrow0 = (long)tn*64;
    j.seg[0] = { h0s(256+t), (long)H_, p.Wext + H_, 6, cnt_h0 + ((256+t)*4+tm) };
    j.seg[1] = { h1s(256+t), (long)H_, p.Wext,      6, cnt_h1 + ((256+t)*4+tm) };
    j.done0 = done_h0 + ((256+t)*4+tm);
    j.done1 = done_h1 + ((256+t)*4+tm);
    if (tn >= 48) {                           // y tile: emits y(t-1)
      j.isY = 1;
      int yc = (tn-48)*64;
      j.ybias = p.bext + NG + yc;
      j.yout = p.out + (long)(T_-t)*F_ + yc;
      return true;
    }
    j.bias = p.bext; j.c = p.c0; j.h = h0s(257+t);
    j.post = cnt_h0 + ((257+t)*4+tm);
    j.ring = done_h0 + ((249+t)*4+tm); j.ringExp = expdone_h0(249+t);
    return true;
  }

  // ---- group B: blocks 200..391
  int i = b - 200;
  if (i >= 192) return false;
  int tm = i & 3, tn = i >> 2;
  j.tm=tm; j.tn=tn; j.b0=tm*32;
  if (s >= 1 && s <= 256) {                   // enc1(t=s-1)
    int t = s - 1;
    j.ldw = 2*H_; j.wrow0 = (long)tn*64;
    j.seg[0] = { h1s(t),   (long)H_, p.Wenc1 + H_, 6, (t>=1) ? cnt_h1 + (t*4+tm) : nullptr };
    j.seg[1] = { h0s(t+1), (long)H_, p.Wenc1,      6, cnt_h0 + ((t+1)*4+tm) };
    j.bias = p.benc1; j.c = p.c1; j.h = h1s(t+1);
    j.post = cnt_h1 + ((t+1)*4+tm);
    if (t+1 >= 8) { j.ring = done_h1 + ((t-7)*4+tm); j.ringExp = expdone_h1(t-7); }
    j.done0 = done_h1 + (t*4+tm);
    j.done1 = done_h0 + ((t+1)*4+tm);
    return true;
  }
  if (s >= 257 && s <= 768) {                 // cd1(t): early=h1 (stale), late=h0 (fresh)
    int d = s - 257;
    if (!(d & 1)) return false;
    int t = d >> 1;
    j.ldw = 2*H_; j.wrow0 = (long)tn*64;
    j.seg[0] = { h1s(256+t), (long)H_, p.Wdec1 + H_, 6, cnt_h1 + ((256+t)*4+tm) };
    j.seg[1] = { h0s(257+t), (long)H_, p.Wdec1,      6, cnt_h0 + ((257+t)*4+tm) };
    j.bias = p.bdec1; j.c = p.c1; j.h = h1s(257+t);
    j.post = cnt_h1 + ((257+t)*4+tm);
    j.ring = done_h1 + ((249+t)*4+tm); j.ringExp = expdone_h1(249+t);
    j.done0 = done_h1 + ((256+t)*4+tm);
    j.done1 = done_h0 + ((257+t)*4+tm);
    return true;
  }
  return false;
}

__global__ __launch_bounds__(256, 1) void lstm_persist(PP p) {
  __shared__ SMu sm;
  int b = blockIdx.x, tid = threadIdx.x;
  int* abortf = p.flags;
  bool alive = true;
  for (int s = 0; s <= 769 && alive; ++s) {
    Job j;
    if (!make_job(s, b, p, j)) continue;
    alive = run_job(j, abortf, sm, tid);
  }
}

// ---------------- prep kernels (round-1, proven) ----------------
__global__ void k_convx(const float* x, unsigned short* xbf, long n) {
  long st = (long)gridDim.x * 256;
  for (long i = (long)blockIdx.x*256 + threadIdx.x; i < n; i += st) xbf[i] = f2bf(x[i]);
}

__global__ void k_init(const float* h0in, const float* c0in,
                       unsigned short* h0slot0, unsigned short* h1slot0,
                       float* c0buf, float* c1buf) {
  int i = blockIdx.x*256 + threadIdx.x;
  if (i < BH) {
    h0slot0[i] = f2bf(h0in[i]);
    h1slot0[i] = f2bf(h0in[BH + i]);
    c0buf[i] = c0in[i];
    c1buf[i] = c0in[BH + i];
  }
}

__global__ __launch_bounds__(256) void k_wcomb(const float* A, const float* Bm, float* Cm) {
  __shared__ float sA[16*128];
  int tid = threadIdx.x;
  int r0 = blockIdx.x * 16;
  int c0 = blockIdx.y * 128;
  for (int e = tid; e < 16*128; e += 256)
    sA[e] = A[(long)(r0 + (e >> 7))*128 + (e & 127)];
  __syncthreads();
  int col = c0 + (tid & 127);
  int rg = (tid >> 7) * 8;
  float acc[8] = {0,0,0,0,0,0,0,0};
  for (int k = 0; k < 128; ++k) {
    float b = Bm[(long)k*768 + col];
#pragma unroll
    for (int r = 0; r < 8; ++r) acc[r] += sA[(rg + r)*128 + k] * b;
  }
  for (int r = 0; r < 8; ++r) Cm[(long)(r0 + rg + r)*768 + col] = acc[r];
}

__global__ void k_bcomb(const float* dWih0, const float* linb, const float* db0, float* bc) {
  int jx = blockIdx.x*256 + threadIdx.x;
  if (jx < NG) {
    float s = db0[jx];
    for (int f = 0; f < 128; ++f) s += dWih0[(long)jx*128 + f] * linb[f];
    bc[jx] = s;
  }
}

__global__ void k_pack(unsigned short* dst, float* bdst, const float* s1, int K1,
                       const float* s2, int K2, const float* bs) {
  long Kt = K1 + K2, total = (long)NG * Kt;
  long st = (long)gridDim.x * 256;
  for (long i = (long)blockIdx.x*256 + threadIdx.x; i < total; i += st) {
    int n = (int)(i / Kt), k = (int)(i % Kt);
    int tn = n >> 6, r = n & 63;
    int jj = (r >> 4)*H_ + tn*UPT + (r & 15);
    float v = (k < K1) ? s1[(long)jj*K1 + k] : s2[(long)jj*K2 + (k - K1)];
    dst[i] = f2bf(v);
    if (k == 0) bdst[n] = bs[jj];
  }
}

__global__ void k_packext(unsigned short* dst, float* bdst, const float* wcomb,
                          const float* whh0, const float* bcomb,
                          const float* linW, const float* linb) {
  long total = (long)(NG + F_) * (2*H_);
  long st = (long)gridDim.x * 256;
  for (long i = (long)blockIdx.x*256 + threadIdx.x; i < total; i += st) {
    int n = (int)(i / (2*H_)), k = (int)(i % (2*H_));
    float v;
    if (n < NG) {
      int tn = n >> 6, r = n & 63;
      int jj = (r >> 4)*H_ + tn*UPT + (r & 15);
      v = (k < H_) ? wcomb[(long)jj*H_ + k] : whh0[(long)jj*H_ + (k - H_)];
      if (k == 0) bdst[n] = bcomb[jj];
    } else {
      int f = n - NG;
      v = (k < H_) ? linW[(long)f*H_ + k] : 0.f;
      if (k == 0) bdst[n] = linb[f];
    }
    dst[i] = f2bf(v);
  }
}

__global__ void k_packlin(unsigned short* dst, const float* linW) {
  int i = blockIdx.x*256 + threadIdx.x;
  if (i < F_*H_) dst[i] = f2bf(linW[i]);
}

// ---------------- host ----------------
extern "C" void kernel_launch(void* const* d_in, const int* in_sizes, int n_in,
                              void* d_out, int out_size, void* d_ws, size_t ws_size,
                              hipStream_t stream)
{
  (void)in_sizes; (void)n_in; (void)out_size; (void)ws_size;
  const float* x     = (const float*)d_in[0];
  const float* h0in  = (const float*)d_in[1];
  const float* c0in  = (const float*)d_in[2];
  const float* eWih0 = (const float*)d_in[3];
  const float* eWhh0 = (const float*)d_in[4];
  const float* eb0   = (const float*)d_in[5];
  const float* eWih1 = (const float*)d_in[6];
  const float* eWhh1 = (const float*)d_in[7];
  const float* eb1   = (const float*)d_in[8];
  const float* dWih0 = (const float*)d_in[9];
  const float* dWhh0 = (const float*)d_in[10];
  const float* db0   = (const float*)d_in[11];
  const float* dWih1 = (const float*)d_in[12];
  const float* dWhh1 = (const float*)d_in[13];
  const float* db1   = (const float*)d_in[14];
  const float* linW  = (const float*)d_in[15];
  const float* linb  = (const float*)d_in[16];
  float* out = (float*)d_out;

  char* wp = (char*)d_ws;
  auto alloc = [&](size_t bytes) -> void* {
    void* p = (void*)wp;
    wp += (bytes + 255) & ~(size_t)255;
    return p;
  };
  int* flags = (int*)alloc((size_t)FL_TOTAL * 4);
  unsigned short* xbf    = (unsigned short*)alloc((size_t)B_*T_*F_*2);
  unsigned short* Wenc0  = (unsigned short*)alloc((size_t)NG*(F_+H_)*2);
  unsigned short* Wenc1  = (unsigned short*)alloc((size_t)NG*(2*H_)*2);
  unsigned short* Wdec0f = (unsigned short*)alloc((size_t)NG*(F_+H_)*2);
  unsigned short* Wext   = (unsigned short*)alloc((size_t)(NG+F_)*(2*H_)*2);
  unsigned short* Wdec1  = (unsigned short*)alloc((size_t)NG*(2*H_)*2);
  unsigned short* linWbf = (unsigned short*)alloc((size_t)F_*H_*2);
  float* Wcomb = (float*)alloc((size_t)NG*H_*4);
  float* benc0 = (float*)alloc((size_t)NG*4);
  float* benc1 = (float*)alloc((size_t)NG*4);
  float* bdec0f= (float*)alloc((size_t)NG*4);
  float* bext  = (float*)alloc((size_t)(NG+F_)*4);
  float* bdec1 = (float*)alloc((size_t)NG*4);
  float* bcomb = (float*)alloc((size_t)NG*4);
  unsigned short* h0ring = (unsigned short*)alloc((size_t)8*BH*2);
  unsigned short* h1ring = (unsigned short*)alloc((size_t)8*BH*2);
  float* c0buf = (float*)alloc((size_t)BH*4);
  float* c1buf = (float*)alloc((size_t)BH*4);

  hipMemsetAsync(flags, 0, (size_t)FL_TOTAL * 4, stream);

  k_convx<<<2048, 256, 0, stream>>>(x, xbf, (long)B_*T_*F_);
  k_init<<<(BH+255)/256, 256, 0, stream>>>(h0in, c0in, h0ring, h1ring, c0buf, c1buf);
  k_wcomb<<<dim3(192,6), 256, 0, stream>>>(dWih0, linW, Wcomb);
  k_bcomb<<<(NG+255)/256, 256, 0, stream>>>(dWih0, linb, db0, bcomb);
  k_pack<<<2048, 256, 0, stream>>>(Wenc0, benc0, eWih0, F_, eWhh0, H_, eb0);
  k_pack<<<2048, 256, 0, stream>>>(Wenc1, benc1, eWih1, H_, eWhh1, H_, eb1);
  k_pack<<<2048, 256, 0, stream>>>(Wdec0f, bdec0f, dWih0, F_, dWhh0, H_, db0);
  k_pack<<<2048, 256, 0, stream>>>(Wdec1, bdec1, dWih1, H_, dWhh1, H_, db1);
  k_packext<<<2048, 256, 0, stream>>>(Wext, bext, Wcomb, dWhh0, bcomb, linW, linb);
  k_packlin<<<(F_*H_+255)/256, 256, 0, stream>>>(linWbf, linW);

  PP p;
  p.xbf = xbf;
  p.Wenc0 = Wenc0; p.Wenc1 = Wenc1; p.Wdec0f = Wdec0f;
  p.Wext = Wext; p.Wdec1 = Wdec1; p.linWbf = linWbf;
  p.benc0 = benc0; p.benc1 = benc1; p.bdec0f = bdec0f;
  p.bext = bext; p.bdec1 = bdec1; p.linb = linb;
  p.h0ring = h0ring; p.h1ring = h1ring;
  p.c0 = c0buf; p.c1 = c1buf;
  p.flags = flags;
  p.out = out;

  lstm_persist<<<392, 256, 0, stream>>>(p);
}